// Round 11
// baseline (147.277 us; speedup 1.0000x reference)
//
#include <hip/hip_runtime.h>
#include <hip/hip_bf16.h>

#define FEAT   1024
#define HID    256
#define TSTEPS 24
#define NCLS   10

typedef unsigned int u32;
typedef unsigned long long u64;
typedef unsigned short u16;
typedef float v2f __attribute__((ext_vector_type(2)));

// ---- workspace layout (float offsets). W1T/W2T/W3T carry one extra ZERO row
// (col 1024 / 256) targeted by list padding -> gathers are pure adds.
constexpr int OFF_W1T  = 0;                     // [1025][256] fp32 (W1^T + zero row)
constexpr int OFF_W2T  = OFF_W1T + 1025*HID;    // [257][256]
constexpr int OFF_W3T  = OFF_W2T + 257*HID;     // [257][256]
constexpr int OFF_WLI  = OFF_W3T + 257*HID;     // [10][256] plain copy
constexpr int OFF_B1   = OFF_WLI + NCLS*HID;
constexpr int OFF_B2   = OFF_B1 + HID;
constexpr int OFF_B3   = OFF_B2 + HID;

// ---- LI readout linearized: vo_24 = sum_t coef[t] * (o3_t @ Wli^T).
struct CoefT { float c[TSTEPS]; };
constexpr CoefT make_coef() {
    CoefT r{};
    double c = 0.0, p9 = 1.0;
    r.c[TSTEPS-1] = 0.0f;
    for (int u = TSTEPS-1; u > 0; u--) {
        c = 0.8 * c + 0.1 * p9;
        p9 *= 0.9;
        r.c[u-1] = (float)c;
    }
    return r;
}
__device__ constexpr CoefT COEF = make_coef();

// ---- in-wave dtype detect: fp32 viewed as bf16 -> exponent garbage at even idx.
__device__ __forceinline__ u32 detect_bf16(const void* __restrict__ x, u32 lane) {
    float v = __bfloat162float(((const __hip_bfloat16*)x)[lane]);
    u64 bad = __ballot(!(fabsf(v) < 100.0f));
    return bad == 0ull ? 1u : 0u;
}

__device__ __forceinline__ float rd_any(const void* p, int idx, u32 isbf) {
    return isbf ? __bfloat162float(((const __hip_bfloat16*)p)[idx])
                : ((const float*)p)[idx];
}

__device__ __forceinline__ float4 rd4(const void* p, int i, u32 isbf) {
    if (isbf) {
        const u32* q = (const u32*)p;
        u32 a = q[i >> 1], b = q[(i >> 1) + 1];
        float4 r;
        r.x = __uint_as_float(a << 16); r.y = __uint_as_float(a & 0xffff0000u);
        r.z = __uint_as_float(b << 16); r.w = __uint_as_float(b & 0xffff0000u);
        return r;
    }
    return ((const float4*)p)[i >> 2];
}

// ---- prep: 32x32 LDS-tiled transpose, coalesced float4 both sides, 385 blocks.
__global__ __launch_bounds__(256) void prep_k(const void* __restrict__ x,
        const void* W1, const void* W2, const void* W3, const void* Wli,
        const void* b1, const void* b2, const void* b3, float* __restrict__ ws) {
    const u32 isbf = detect_bf16(x, threadIdx.x & 63);
    const u32 t = threadIdx.x;
    int b = blockIdx.x;

    if (b == 384) {   // tail: Wli + biases + zero rows (all coalesced)
        for (u32 e = t; e < NCLS*HID; e += 256) ws[OFF_WLI + e] = rd_any(Wli, e, isbf);
        ws[OFF_B1 + t] = rd_any(b1, t, isbf);
        ws[OFF_B2 + t] = rd_any(b2, t, isbf);
        ws[OFF_B3 + t] = rd_any(b3, t, isbf);
        ws[OFF_W1T + 1024*HID + t] = 0.f;
        ws[OFF_W2T + 256*HID + t] = 0.f;
        ws[OFF_W3T + 256*HID + t] = 0.f;
        return;
    }

    const void* src; float* dst; int srcW, h0, f0;
    if (b < 256)      { src = W1; dst = ws + OFF_W1T; srcW = FEAT; h0 = (b >> 5) * 32; f0 = (b & 31) * 32; }
    else if (b < 320) { int tb = b - 256; src = W2; dst = ws + OFF_W2T; srcW = HID; h0 = (tb >> 3) * 32; f0 = (tb & 7) * 32; }
    else              { int tb = b - 320; src = W3; dst = ws + OFF_W3T; srcW = HID; h0 = (tb >> 3) * 32; f0 = (tb & 7) * 32; }

    __shared__ float sm[32 * 36];
    {
        u32 r = t >> 3, c4 = (t & 7) * 4;
        float4 w = rd4(src, (h0 + r) * srcW + f0 + c4, isbf);
        *(float4*)&sm[r * 36 + c4] = w;
    }
    __syncthreads();
    {
        u32 f = t >> 3, h4 = (t & 7) * 4;
        float4 o;
        o.x = sm[(h4 + 0) * 36 + f];
        o.y = sm[(h4 + 1) * 36 + f];
        o.z = sm[(h4 + 2) * 36 + f];
        o.w = sm[(h4 + 3) * 36 + f];
        *(float4*)&dst[(size_t)(f0 + f) * HID + h0 + h4] = o;
    }
}

__device__ __forceinline__ u32 mbcnt64(u64 m) {
    return __builtin_amdgcn_mbcnt_hi((u32)(m >> 32),
           __builtin_amdgcn_mbcnt_lo((u32)m, 0u));
}

// ---- list builders: u16 col-index entries; branch-free prefix via weighted
// bit-plane ballots; pad to multiple of 4 with the zero-row col. ----

// encoder: 16 features/lane, col = 16*lane + j; zero col = 1024. returns padded np.
__device__ __forceinline__ u32 build_listE(u16* list, u32 lm, u32 lane) {
    u32 cnt = (u32)__builtin_popcount(lm);
    u32 pos = 0, n = 0;
    #pragma unroll
    for (int b = 0; b < 5; b++) {
        u64 B = __ballot(((cnt >> b) & 1u) != 0);
        pos += mbcnt64(B) << b;
        n += ((u32)__builtin_popcountll(B)) << b;
    }
    while (lm) {
        u32 j = (u32)__builtin_ctz(lm); lm &= lm - 1;
        list[pos++] = (u16)((lane << 4) + j);
    }
    u32 np = (n + 3u) & ~3u;
    if (lane < np - n) list[n + lane] = (u16)1024;
    return np;
}

// z layers: 4 neurons/lane, col = 4*lane + j; zero col = 256; append at start.
// Returns {n (real end), np (padded end, multiple of 4)}.
__device__ __forceinline__ uint2 build_listZ(u16* list, u32 lm, u32 start, u32 lane) {
    u32 cnt = (u32)__builtin_popcount(lm);
    u64 B0 = __ballot((cnt & 1u) != 0);
    u64 B1 = __ballot((cnt & 2u) != 0);
    u64 B2 = __ballot((cnt & 4u) != 0);
    u32 pos = start + mbcnt64(B0) + 2u*mbcnt64(B1) + 4u*mbcnt64(B2);
    u32 n = start + (u32)__builtin_popcountll(B0) + 2u*(u32)__builtin_popcountll(B1)
          + 4u*(u32)__builtin_popcountll(B2);
    while (lm) {
        u32 j = (u32)__builtin_ctz(lm); lm &= lm - 1;
        list[pos++] = (u16)((lane << 2) + j);
    }
    u32 np = (n + 3u) & ~3u;
    if (lane < np - n) list[n + lane] = (u16)256;
    return make_uint2(n, np);
}

#define GADD(V) do { A += (v2f){(V).x, (V).y}; B += (v2f){(V).z, (V).w}; } while (0)

// ---- gather: main chunks of 8 (1 ds_read_b128 -> 8 loads -> 16 pk_add),
// one uniform chunk-4 tail. np must be a multiple of 4. Pads hit zero row. ----
__device__ __forceinline__ void gather(v2f& A, v2f& B, const float* __restrict__ Wt,
                                       const u16* __restrict__ list, u32 np, u32 lane16) {
    const char* __restrict__ base = (const char*)Wt;
    u32 c = 0;
    for (; c + 8 <= np; c += 8) {
        uint4 d = *(const uint4*)(list + c);       // 8 u16 entries
        const float4 v0 = *(const float4*)(base + ((d.x & 0xffffu) << 10) + lane16);
        const float4 v1 = *(const float4*)(base + ((d.x >> 16)     << 10) + lane16);
        const float4 v2 = *(const float4*)(base + ((d.y & 0xffffu) << 10) + lane16);
        const float4 v3 = *(const float4*)(base + ((d.y >> 16)     << 10) + lane16);
        const float4 v4 = *(const float4*)(base + ((d.z & 0xffffu) << 10) + lane16);
        const float4 v5 = *(const float4*)(base + ((d.z >> 16)     << 10) + lane16);
        const float4 v6 = *(const float4*)(base + ((d.w & 0xffffu) << 10) + lane16);
        const float4 v7 = *(const float4*)(base + ((d.w >> 16)     << 10) + lane16);
        GADD(v0); GADD(v1); GADD(v2); GADD(v3);
        GADD(v4); GADD(v5); GADD(v6); GADD(v7);
    }
    if (c < np) {                                  // exactly 4 remain
        uint2 d = *(const uint2*)(list + c);
        const float4 v0 = *(const float4*)(base + ((d.x & 0xffffu) << 10) + lane16);
        const float4 v1 = *(const float4*)(base + ((d.x >> 16)     << 10) + lane16);
        const float4 v2 = *(const float4*)(base + ((d.y & 0xffffu) << 10) + lane16);
        const float4 v3 = *(const float4*)(base + ((d.y >> 16)     << 10) + lane16);
        GADD(v0); GADD(v1); GADD(v2); GADD(v3);
    }
}

// ONE wave = ONE block = ONE batch row (finest dispatch grain: no intra-block
// wave coupling, minimal tail quantum). Lane owns encoder features
// [16L..16L+16) and hidden neurons 4L..4L+3. Encoder spike schedule
// precomputed to LDS (2 steps/u32). z1 list shared by L2 (W2T) and L3 (W3T);
// z2 appended at UNPADDED n1 so L3 pads only once.
__global__ __launch_bounds__(64) void snn_k(const void* __restrict__ xin,
                                            const float* __restrict__ ws,
                                            void* __restrict__ out) {
    const u32 lane = threadIdx.x;
    const int row  = blockIdx.x;
    const u32 lane16 = lane * 16;
    const u32 isbf = detect_bf16(xin, lane);

    const float* __restrict__ W1T = ws + OFF_W1T;
    const float* __restrict__ W2T = ws + OFF_W2T;
    const float* __restrict__ W3T = ws + OFF_W3T;
    const float* __restrict__ WLI = ws + OFF_WLI;

    __shared__ u32 sched[12 * 64];               // 3 KB
    __shared__ __align__(16) u16 lE[1032];       // 2 KB
    __shared__ __align__(16) u16 lL[520];        // 1 KB

    // ---- encoder precompute: 24-step spike schedule for my 16 features ----
    {
        float xv[16];
        if (isbf) {
            const uint4* xp = (const uint4*)((const u16*)xin + (size_t)row*FEAT + lane*16);
            uint4 A = xp[0], B = xp[1];
            u32 w[8] = {A.x, A.y, A.z, A.w, B.x, B.y, B.z, B.w};
            #pragma unroll
            for (int i = 0; i < 8; i++) {
                xv[2*i]   = __uint_as_float(w[i] << 16);
                xv[2*i+1] = __uint_as_float(w[i] & 0xffff0000u);
            }
        } else {
            const float4* xp = (const float4*)((const float*)xin + (size_t)row*FEAT + lane*16);
            float4 A = xp[0], B = xp[1], C = xp[2], D = xp[3];
            float tmp[16] = {A.x,A.y,A.z,A.w,B.x,B.y,B.z,B.w,C.x,C.y,C.z,C.w,D.x,D.y,D.z,D.w};
            #pragma unroll
            for (int i = 0; i < 16; i++) xv[i] = tmp[i];
        }
        u32 smreg[12];
        #pragma unroll
        for (int i = 0; i < 12; i++) smreg[i] = 0;
        #pragma unroll
        for (int j = 0; j < 16; j++) {
            float v = 0.f;
            #pragma unroll
            for (int t = 0; t < TSTEPS; t++) {
                v = v + 0.1f * (xv[j] - v);
                bool z = v > 1.0f;
                v = z ? 0.0f : v;
                if (z) smreg[t >> 1] |= 1u << (((t & 1) << 4) + j);
            }
        }
        #pragma unroll
        for (int i = 0; i < 12; i++) sched[i * 64 + lane] = smreg[i];
        // lanes read back only their own words -> no barrier needed
    }

    float v1[4], i1[4], v2[4], i2[4], v3[4], i3[4], g[4];
    #pragma unroll
    for (int k = 0; k < 4; k++) {
        v1[k]=0.f; i1[k]=0.f; v2[k]=0.f; i2[k]=0.f; v3[k]=0.f; i3[k]=0.f; g[k]=0.f;
    }
    const u32 lane4 = lane * 4;
    const float4 b1v = *(const float4*)(ws + OFF_B1 + lane4);
    const float4 b2v = *(const float4*)(ws + OFF_B2 + lane4);
    const float4 b3v = *(const float4*)(ws + OFF_B3 + lane4);

    u32 pairreg = 0;
    for (int t = 0; t < TSTEPS; t++) {
        if ((t & 1) == 0) pairreg = sched[(t >> 1) * 64 + lane];
        const u32 lmE = (t & 1) ? (pairreg >> 16) : (pairreg & 0xffffu);

        // ---- layer 1 ----
        u32 npE = build_listE(lE, lmE, lane);
        v2f accA = {b1v.x, b1v.y}, accB = {b1v.z, b1v.w};
        gather(accA, accB, W1T, lE, npE, lane16);
        float a1[4] = {accA.x, accA.y, accB.x, accB.y};

        float o1v[4]; u32 lm1 = 0;
        #pragma unroll
        for (int kk = 0; kk < 4; kk++) {
            float vd = v1[kk] + 0.1f * (i1[kk] - v1[kk]);
            i1[kk] = i1[kk] * 0.8f;
            bool z = vd > 0.23f;
            v1[kk] = z ? 0.0f : vd;
            i1[kk] = i1[kk] + a1[kk];
            o1v[kk] = z ? 1.0f : 0.0f;
            lm1 |= (z ? 1u : 0u) << kk;
        }

        // ---- layer 2: z1 cols on W2T (gather incl. z1 pads) ----
        uint2 r1 = build_listZ(lL, lm1, 0u, lane);
        accA = (v2f){b2v.x, b2v.y}; accB = (v2f){b2v.z, b2v.w};
        gather(accA, accB, W2T, lL, r1.y, lane16);
        float a2[4] = {accA.x, accA.y, accB.x, accB.y};

        float o2v[4]; u32 lm2 = 0;
        #pragma unroll
        for (int kk = 0; kk < 4; kk++) {
            float vd = v2[kk] + 0.1f * (i2[kk] - v2[kk]);
            i2[kk] = i2[kk] * 0.8f;
            bool z = vd > 0.23f;
            v2[kk] = z ? 0.0f : vd;
            i2[kk] = i2[kk] + a2[kk];
            o2v[kk] = (z ? 1.0f : 0.0f) + o1v[kk];
            lm2 |= (z ? 1u : 0u) << kk;
        }

        // ---- layer 3: append z2 at UNPADDED n1 (overwrites z1 pads, already
        //      consumed); one contiguous gather [0, np2) on W3T. o2 = z1 + z2
        //      via duplicate cols (exact). ----
        uint2 r2 = build_listZ(lL, lm2, r1.x, lane);
        v2f acc3A = {b3v.x, b3v.y}, acc3B = {b3v.z, b3v.w};
        gather(acc3A, acc3B, W3T, lL, r2.y, lane16);
        float a3[4] = {acc3A.x, acc3A.y, acc3B.x, acc3B.y};

        const float cf = COEF.c[t];
        #pragma unroll
        for (int kk = 0; kk < 4; kk++) {
            float vd = v3[kk] + 0.1f * (i3[kk] - v3[kk]);
            i3[kk] = i3[kk] * 0.8f;
            bool z = vd > 0.23f;
            v3[kk] = z ? 0.0f : vd;
            i3[kk] = i3[kk] + a3[kk];
            float o3 = (z ? 1.0f : 0.0f) + o2v[kk];
            g[kk] += cf * o3;
        }
    }

    // ---- epilogue: vo_24[c] = sum_h g[h]*Wli[c][h] ----
    float s[NCLS];
    #pragma unroll
    for (int c = 0; c < NCLS; c++) {
        const float4 w = *(const float4*)(WLI + c*HID + lane4);
        float p = g[0]*w.x + g[1]*w.y + g[2]*w.z + g[3]*w.w;
        #pragma unroll
        for (int d = 32; d > 0; d >>= 1) p += __shfl_xor(p, d, 64);
        s[c] = p;
    }
    if (lane == 0) {
        if (isbf) {
            __hip_bfloat16* o = (__hip_bfloat16*)out + (size_t)row*NCLS;
            #pragma unroll
            for (int c = 0; c < NCLS; c++) o[c] = __float2bfloat16(s[c]);
        } else {
            float* o = (float*)out + (size_t)row*NCLS;
            #pragma unroll
            for (int c = 0; c < NCLS; c++) o[c] = s[c];
        }
    }
}

extern "C" void kernel_launch(void* const* d_in, const int* in_sizes, int n_in,
                              void* d_out, int out_size, void* d_ws, size_t ws_size,
                              hipStream_t stream) {
    const void* x   = d_in[0];
    const void* W1  = d_in[1];
    const void* b1  = d_in[2];
    const void* W2  = d_in[3];
    const void* b2  = d_in[4];
    const void* W3  = d_in[5];
    const void* b3  = d_in[6];
    const void* Wli = d_in[7];
    float* ws = (float*)d_ws;
    const int batch = in_sizes[0] / FEAT;   // 4096

    prep_k<<<385, 256, 0, stream>>>(x, W1, W2, W3, Wli, b1, b2, b3, ws);
    snn_k<<<batch, 64, 0, stream>>>(x, ws, d_out);
}

// Round 12
// 143.982 us; speedup vs baseline: 1.0229x; 1.0229x over previous
//
#include <hip/hip_runtime.h>
#include <hip/hip_bf16.h>

#define FEAT   1024
#define HID    256
#define TSTEPS 24
#define NCLS   10

typedef unsigned int u32;
typedef unsigned long long u64;
typedef unsigned short u16;
typedef float v2f __attribute__((ext_vector_type(2)));

// ---- workspace layout (float offsets). W1T/W2T/W3T carry one extra ZERO row
// (col 1024 / 256) targeted by list padding -> gathers are pure adds.
constexpr int OFF_W1T  = 0;                     // [1025][256] fp32 (W1^T + zero row)
constexpr int OFF_W2T  = OFF_W1T + 1025*HID;    // [257][256]
constexpr int OFF_W3T  = OFF_W2T + 257*HID;     // [257][256]
constexpr int OFF_WLI  = OFF_W3T + 257*HID;     // [10][256] plain copy
constexpr int OFF_B1   = OFF_WLI + NCLS*HID;
constexpr int OFF_B2   = OFF_B1 + HID;
constexpr int OFF_B3   = OFF_B2 + HID;

// ---- LI readout linearized: vo_24 = sum_t coef[t] * (o3_t @ Wli^T).
struct CoefT { float c[TSTEPS]; };
constexpr CoefT make_coef() {
    CoefT r{};
    double c = 0.0, p9 = 1.0;
    r.c[TSTEPS-1] = 0.0f;
    for (int u = TSTEPS-1; u > 0; u--) {
        c = 0.8 * c + 0.1 * p9;
        p9 *= 0.9;
        r.c[u-1] = (float)c;
    }
    return r;
}
__device__ constexpr CoefT COEF = make_coef();

// ---- in-wave dtype detect: fp32 viewed as bf16 -> exponent garbage at even idx.
__device__ __forceinline__ u32 detect_bf16(const void* __restrict__ x, u32 lane) {
    float v = __bfloat162float(((const __hip_bfloat16*)x)[lane]);
    u64 bad = __ballot(!(fabsf(v) < 100.0f));
    return bad == 0ull ? 1u : 0u;
}

__device__ __forceinline__ float rd_any(const void* p, int idx, u32 isbf) {
    return isbf ? __bfloat162float(((const __hip_bfloat16*)p)[idx])
                : ((const float*)p)[idx];
}

__device__ __forceinline__ float4 rd4(const void* p, int i, u32 isbf) {
    if (isbf) {
        const u32* q = (const u32*)p;
        u32 a = q[i >> 1], b = q[(i >> 1) + 1];
        float4 r;
        r.x = __uint_as_float(a << 16); r.y = __uint_as_float(a & 0xffff0000u);
        r.z = __uint_as_float(b << 16); r.w = __uint_as_float(b & 0xffff0000u);
        return r;
    }
    return ((const float4*)p)[i >> 2];
}

// ---- prep: 32x32 LDS-tiled transpose, coalesced float4 both sides, 385 blocks.
__global__ __launch_bounds__(256) void prep_k(const void* __restrict__ x,
        const void* W1, const void* W2, const void* W3, const void* Wli,
        const void* b1, const void* b2, const void* b3, float* __restrict__ ws) {
    const u32 isbf = detect_bf16(x, threadIdx.x & 63);
    const u32 t = threadIdx.x;
    int b = blockIdx.x;

    if (b == 384) {   // tail: Wli + biases + zero rows (all coalesced)
        for (u32 e = t; e < NCLS*HID; e += 256) ws[OFF_WLI + e] = rd_any(Wli, e, isbf);
        ws[OFF_B1 + t] = rd_any(b1, t, isbf);
        ws[OFF_B2 + t] = rd_any(b2, t, isbf);
        ws[OFF_B3 + t] = rd_any(b3, t, isbf);
        ws[OFF_W1T + 1024*HID + t] = 0.f;
        ws[OFF_W2T + 256*HID + t] = 0.f;
        ws[OFF_W3T + 256*HID + t] = 0.f;
        return;
    }

    const void* src; float* dst; int srcW, h0, f0;
    if (b < 256)      { src = W1; dst = ws + OFF_W1T; srcW = FEAT; h0 = (b >> 5) * 32; f0 = (b & 31) * 32; }
    else if (b < 320) { int tb = b - 256; src = W2; dst = ws + OFF_W2T; srcW = HID; h0 = (tb >> 3) * 32; f0 = (tb & 7) * 32; }
    else              { int tb = b - 320; src = W3; dst = ws + OFF_W3T; srcW = HID; h0 = (tb >> 3) * 32; f0 = (tb & 7) * 32; }

    __shared__ float sm[32 * 36];
    {
        u32 r = t >> 3, c4 = (t & 7) * 4;
        float4 w = rd4(src, (h0 + r) * srcW + f0 + c4, isbf);
        *(float4*)&sm[r * 36 + c4] = w;
    }
    __syncthreads();
    {
        u32 f = t >> 3, h4 = (t & 7) * 4;
        float4 o;
        o.x = sm[(h4 + 0) * 36 + f];
        o.y = sm[(h4 + 1) * 36 + f];
        o.z = sm[(h4 + 2) * 36 + f];
        o.w = sm[(h4 + 3) * 36 + f];
        *(float4*)&dst[(size_t)(f0 + f) * HID + h0 + h4] = o;
    }
}

__device__ __forceinline__ u32 mbcnt64(u64 m) {
    return __builtin_amdgcn_mbcnt_hi((u32)(m >> 32),
           __builtin_amdgcn_mbcnt_lo((u32)m, 0u));
}

// ---- list builders: u16 col-index entries; branch-free prefix via weighted
// bit-plane ballots; pad to EVEN count with the zero-row col. ----

// encoder: 16 features/lane, col = 16*lane + j; zero col = 1024. returns padded np.
__device__ __forceinline__ u32 build_listE(u16* list, u32 lm, u32 lane) {
    u32 cnt = (u32)__builtin_popcount(lm);
    u32 pos = 0, n = 0;
    #pragma unroll
    for (int b = 0; b < 5; b++) {
        u64 B = __ballot(((cnt >> b) & 1u) != 0);
        pos += mbcnt64(B) << b;
        n += ((u32)__builtin_popcountll(B)) << b;
    }
    while (lm) {
        u32 j = (u32)__builtin_ctz(lm); lm &= lm - 1;
        list[pos++] = (u16)((lane << 4) + j);
    }
    u32 np = (n + 1u) & ~1u;
    if (lane == 0 && np != n) list[n] = (u16)1024;
    return np;
}

// z layers: 4 neurons/lane, col = 4*lane + j; zero col = 256; append at start
// (start must be even). returns padded end (even).
__device__ __forceinline__ u32 build_listZ(u16* list, u32 lm, u32 start, u32 lane) {
    u32 cnt = (u32)__builtin_popcount(lm);
    u64 B0 = __ballot((cnt & 1u) != 0);
    u64 B1 = __ballot((cnt & 2u) != 0);
    u64 B2 = __ballot((cnt & 4u) != 0);
    u32 pos = start + mbcnt64(B0) + 2u*mbcnt64(B1) + 4u*mbcnt64(B2);
    u32 n = start + (u32)__builtin_popcountll(B0) + 2u*(u32)__builtin_popcountll(B1)
          + 4u*(u32)__builtin_popcountll(B2);
    while (lm) {
        u32 j = (u32)__builtin_ctz(lm); lm &= lm - 1;
        list[pos++] = (u16)((lane << 2) + j);
    }
    u32 np = (n + 1u) & ~1u;
    if (lane == 0 && np != n) list[n] = (u16)256;
    return np;
}

#define GADD(AA, BB, V) do { AA += (v2f){(V).x, (V).y}; BB += (v2f){(V).z, (V).w}; } while (0)

// ---- gather (single matrix): chunks of 8 + 2-col unit tail. np even. ----
__device__ __forceinline__ void gather(v2f& A, v2f& B, const float* __restrict__ Wt,
                                       const u16* __restrict__ list, u32 np, u32 lane16) {
    const char* __restrict__ base = (const char*)Wt;
    u32 c = 0;
    for (; c + 8 <= np; c += 8) {
        uint4 d = *(const uint4*)(list + c);
        const float4 v0 = *(const float4*)(base + ((d.x & 0xffffu) << 10) + lane16);
        const float4 v1 = *(const float4*)(base + ((d.x >> 16)     << 10) + lane16);
        const float4 v2 = *(const float4*)(base + ((d.y & 0xffffu) << 10) + lane16);
        const float4 v3 = *(const float4*)(base + ((d.y >> 16)     << 10) + lane16);
        const float4 v4 = *(const float4*)(base + ((d.z & 0xffffu) << 10) + lane16);
        const float4 v5 = *(const float4*)(base + ((d.z >> 16)     << 10) + lane16);
        const float4 v6 = *(const float4*)(base + ((d.w & 0xffffu) << 10) + lane16);
        const float4 v7 = *(const float4*)(base + ((d.w >> 16)     << 10) + lane16);
        GADD(A, B, v0); GADD(A, B, v1); GADD(A, B, v2); GADD(A, B, v3);
        GADD(A, B, v4); GADD(A, B, v5); GADD(A, B, v6); GADD(A, B, v7);
    }
    for (; c < np; c += 2) {                      // 2-col units (4-B aligned)
        u32 d = *(const u32*)(list + c);
        const float4 v0 = *(const float4*)(base + ((d & 0xffffu) << 10) + lane16);
        const float4 v1 = *(const float4*)(base + ((d >> 16)     << 10) + lane16);
        GADD(A, B, v0); GADD(A, B, v1);
    }
}

// ---- dual gather over the z1 segment: same cols on W2T and W3T in one pass
// (8 loads in flight per 4-col unit; one ds_read; identical per-acc order). ----
__device__ __forceinline__ void gather_dual(v2f& A2, v2f& B2, v2f& A3, v2f& B3,
        const float* __restrict__ W2t, const float* __restrict__ W3t,
        const u16* __restrict__ list, u32 np, u32 lane16) {
    const char* __restrict__ b2 = (const char*)W2t;
    const char* __restrict__ b3 = (const char*)W3t;
    u32 c = 0;
    for (; c + 4 <= np; c += 4) {
        uint2 d = *(const uint2*)(list + c);
        u32 o0 = (d.x & 0xffffu) << 10, o1 = (d.x >> 16) << 10;
        u32 o2 = (d.y & 0xffffu) << 10, o3 = (d.y >> 16) << 10;
        const float4 a0 = *(const float4*)(b2 + o0 + lane16);
        const float4 a1 = *(const float4*)(b2 + o1 + lane16);
        const float4 a2 = *(const float4*)(b2 + o2 + lane16);
        const float4 a3 = *(const float4*)(b2 + o3 + lane16);
        const float4 c0 = *(const float4*)(b3 + o0 + lane16);
        const float4 c1 = *(const float4*)(b3 + o1 + lane16);
        const float4 c2 = *(const float4*)(b3 + o2 + lane16);
        const float4 c3 = *(const float4*)(b3 + o3 + lane16);
        GADD(A2, B2, a0); GADD(A2, B2, a1); GADD(A2, B2, a2); GADD(A2, B2, a3);
        GADD(A3, B3, c0); GADD(A3, B3, c1); GADD(A3, B3, c2); GADD(A3, B3, c3);
    }
    for (; c < np; c += 2) {
        u32 d = *(const u32*)(list + c);
        u32 o0 = (d & 0xffffu) << 10, o1 = (d >> 16) << 10;
        const float4 a0 = *(const float4*)(b2 + o0 + lane16);
        const float4 a1 = *(const float4*)(b2 + o1 + lane16);
        const float4 c0 = *(const float4*)(b3 + o0 + lane16);
        const float4 c1 = *(const float4*)(b3 + o1 + lane16);
        GADD(A2, B2, a0); GADD(A2, B2, a1);
        GADD(A3, B3, c0); GADD(A3, B3, c1);
    }
}

// ONE wave = ONE block = ONE batch row. Lane owns encoder features
// [16L..16L+16) and hidden neurons 4L..4L+3. Encoder spike schedule
// precomputed to LDS (2 steps/u32). z1 segment feeds L2 and L3 in one dual
// pass; z2 appended at padded np1. Empty-mask fast paths skip build+gather.
__global__ __launch_bounds__(64) void snn_k(const void* __restrict__ xin,
                                            const float* __restrict__ ws,
                                            void* __restrict__ out) {
    const u32 lane = threadIdx.x;
    const int row  = blockIdx.x;
    const u32 lane16 = lane * 16;
    const u32 isbf = detect_bf16(xin, lane);

    const float* __restrict__ W1T = ws + OFF_W1T;
    const float* __restrict__ W2T = ws + OFF_W2T;
    const float* __restrict__ W3T = ws + OFF_W3T;
    const float* __restrict__ WLI = ws + OFF_WLI;

    __shared__ u32 sched[12 * 64];               // 3 KB
    __shared__ __align__(16) u16 lE[1032];       // 2 KB
    __shared__ __align__(16) u16 lL[520];        // 1 KB

    // ---- encoder precompute: 24-step spike schedule for my 16 features ----
    {
        float xv[16];
        if (isbf) {
            const uint4* xp = (const uint4*)((const u16*)xin + (size_t)row*FEAT + lane*16);
            uint4 A = xp[0], B = xp[1];
            u32 w[8] = {A.x, A.y, A.z, A.w, B.x, B.y, B.z, B.w};
            #pragma unroll
            for (int i = 0; i < 8; i++) {
                xv[2*i]   = __uint_as_float(w[i] << 16);
                xv[2*i+1] = __uint_as_float(w[i] & 0xffff0000u);
            }
        } else {
            const float4* xp = (const float4*)((const float*)xin + (size_t)row*FEAT + lane*16);
            float4 A = xp[0], B = xp[1], C = xp[2], D = xp[3];
            float tmp[16] = {A.x,A.y,A.z,A.w,B.x,B.y,B.z,B.w,C.x,C.y,C.z,C.w,D.x,D.y,D.z,D.w};
            #pragma unroll
            for (int i = 0; i < 16; i++) xv[i] = tmp[i];
        }
        u32 smreg[12];
        #pragma unroll
        for (int i = 0; i < 12; i++) smreg[i] = 0;
        #pragma unroll
        for (int j = 0; j < 16; j++) {
            float v = 0.f;
            #pragma unroll
            for (int t = 0; t < TSTEPS; t++) {
                v = v + 0.1f * (xv[j] - v);
                bool z = v > 1.0f;
                v = z ? 0.0f : v;
                if (z) smreg[t >> 1] |= 1u << (((t & 1) << 4) + j);
            }
        }
        #pragma unroll
        for (int i = 0; i < 12; i++) sched[i * 64 + lane] = smreg[i];
        // lanes read back only their own words -> no barrier needed
    }

    float v1[4], i1[4], v2[4], i2[4], v3[4], i3[4], g[4];
    #pragma unroll
    for (int k = 0; k < 4; k++) {
        v1[k]=0.f; i1[k]=0.f; v2[k]=0.f; i2[k]=0.f; v3[k]=0.f; i3[k]=0.f; g[k]=0.f;
    }
    const u32 lane4 = lane * 4;
    const float4 b1v = *(const float4*)(ws + OFF_B1 + lane4);
    const float4 b2v = *(const float4*)(ws + OFF_B2 + lane4);
    const float4 b3v = *(const float4*)(ws + OFF_B3 + lane4);

    u32 pairreg = 0;
    for (int t = 0; t < TSTEPS; t++) {
        if ((t & 1) == 0) pairreg = sched[(t >> 1) * 64 + lane];
        const u32 lmE = (t & 1) ? (pairreg >> 16) : (pairreg & 0xffffu);

        // ---- layer 1 (skip build+gather if no encoder spikes this step) ----
        v2f accA = {b1v.x, b1v.y}, accB = {b1v.z, b1v.w};
        if (__ballot(lmE != 0u)) {
            u32 npE = build_listE(lE, lmE, lane);
            gather(accA, accB, W1T, lE, npE, lane16);
        }
        float a1[4] = {accA.x, accA.y, accB.x, accB.y};

        float o1v[4]; u32 lm1 = 0;
        #pragma unroll
        for (int kk = 0; kk < 4; kk++) {
            float vd = v1[kk] + 0.1f * (i1[kk] - v1[kk]);
            i1[kk] = i1[kk] * 0.8f;
            bool z = vd > 0.23f;
            v1[kk] = z ? 0.0f : vd;
            i1[kk] = i1[kk] + a1[kk];
            o1v[kk] = z ? 1.0f : 0.0f;
            lm1 |= (z ? 1u : 0u) << kk;
        }

        // ---- layers 2+3a: z1 cols, dual gather on W2T & W3T ----
        v2f acc2A = {b2v.x, b2v.y}, acc2B = {b2v.z, b2v.w};
        v2f acc3A = {b3v.x, b3v.y}, acc3B = {b3v.z, b3v.w};
        u32 np1 = 0;
        if (__ballot(lm1 != 0u)) {
            np1 = build_listZ(lL, lm1, 0u, lane);
            gather_dual(acc2A, acc2B, acc3A, acc3B, W2T, W3T, lL, np1, lane16);
        }
        float a2[4] = {acc2A.x, acc2A.y, acc2B.x, acc2B.y};

        float o2v[4]; u32 lm2 = 0;
        #pragma unroll
        for (int kk = 0; kk < 4; kk++) {
            float vd = v2[kk] + 0.1f * (i2[kk] - v2[kk]);
            i2[kk] = i2[kk] * 0.8f;
            bool z = vd > 0.23f;
            v2[kk] = z ? 0.0f : vd;
            i2[kk] = i2[kk] + a2[kk];
            o2v[kk] = (z ? 1.0f : 0.0f) + o1v[kk];
            lm2 |= (z ? 1u : 0u) << kk;
        }

        // ---- layer 3b: append z2 at padded np1, gather [np1, np2) on W3T.
        //      o2 = z1 + z2 via duplicate cols (exact). ----
        if (__ballot(lm2 != 0u)) {
            u32 np2 = build_listZ(lL, lm2, np1, lane);
            gather(acc3A, acc3B, W3T, lL + np1, np2 - np1, lane16);
        }
        float a3[4] = {acc3A.x, acc3A.y, acc3B.x, acc3B.y};

        const float cf = COEF.c[t];
        #pragma unroll
        for (int kk = 0; kk < 4; kk++) {
            float vd = v3[kk] + 0.1f * (i3[kk] - v3[kk]);
            i3[kk] = i3[kk] * 0.8f;
            bool z = vd > 0.23f;
            v3[kk] = z ? 0.0f : vd;
            i3[kk] = i3[kk] + a3[kk];
            float o3 = (z ? 1.0f : 0.0f) + o2v[kk];
            g[kk] += cf * o3;
        }
    }

    // ---- epilogue: vo_24[c] = sum_h g[h]*Wli[c][h] ----
    float s[NCLS];
    #pragma unroll
    for (int c = 0; c < NCLS; c++) {
        const float4 w = *(const float4*)(WLI + c*HID + lane4);
        float p = g[0]*w.x + g[1]*w.y + g[2]*w.z + g[3]*w.w;
        #pragma unroll
        for (int d = 32; d > 0; d >>= 1) p += __shfl_xor(p, d, 64);
        s[c] = p;
    }
    if (lane == 0) {
        if (isbf) {
            __hip_bfloat16* o = (__hip_bfloat16*)out + (size_t)row*NCLS;
            #pragma unroll
            for (int c = 0; c < NCLS; c++) o[c] = __float2bfloat16(s[c]);
        } else {
            float* o = (float*)out + (size_t)row*NCLS;
            #pragma unroll
            for (int c = 0; c < NCLS; c++) o[c] = s[c];
        }
    }
}

extern "C" void kernel_launch(void* const* d_in, const int* in_sizes, int n_in,
                              void* d_out, int out_size, void* d_ws, size_t ws_size,
                              hipStream_t stream) {
    const void* x   = d_in[0];
    const void* W1  = d_in[1];
    const void* b1  = d_in[2];
    const void* W2  = d_in[3];
    const void* b2  = d_in[4];
    const void* W3  = d_in[5];
    const void* b3  = d_in[6];
    const void* Wli = d_in[7];
    float* ws = (float*)d_ws;
    const int batch = in_sizes[0] / FEAT;   // 4096

    prep_k<<<385, 256, 0, stream>>>(x, W1, W2, W3, Wli, b1, b2, b3, ws);
    snn_k<<<batch, 64, 0, stream>>>(x, ws, d_out);
}

// Round 13
// 143.435 us; speedup vs baseline: 1.0268x; 1.0038x over previous
//
#include <hip/hip_runtime.h>
#include <hip/hip_bf16.h>

#define FEAT   1024
#define HID    256
#define TSTEPS 24
#define NCLS   10

typedef unsigned int u32;
typedef unsigned long long u64;
typedef unsigned short u16;
typedef float v2f __attribute__((ext_vector_type(2)));

// ---- workspace layout (float offsets). W1T/W2T/W3T carry one extra ZERO row
// (col 1024 / 256) targeted by list padding -> gathers are pure adds.
constexpr int OFF_W1T  = 0;                     // [1025][256] fp32 (W1^T + zero row)
constexpr int OFF_W2T  = OFF_W1T + 1025*HID;    // [257][256]
constexpr int OFF_W3T  = OFF_W2T + 257*HID;     // [257][256]
constexpr int OFF_WLI  = OFF_W3T + 257*HID;     // [10][256] plain copy
constexpr int OFF_B1   = OFF_WLI + NCLS*HID;
constexpr int OFF_B2   = OFF_B1 + HID;
constexpr int OFF_B3   = OFF_B2 + HID;

// ---- LI readout linearized: vo_24 = sum_t coef[t] * (o3_t @ Wli^T).
struct CoefT { float c[TSTEPS]; };
constexpr CoefT make_coef() {
    CoefT r{};
    double c = 0.0, p9 = 1.0;
    r.c[TSTEPS-1] = 0.0f;
    for (int u = TSTEPS-1; u > 0; u--) {
        c = 0.8 * c + 0.1 * p9;
        p9 *= 0.9;
        r.c[u-1] = (float)c;
    }
    return r;
}
__device__ constexpr CoefT COEF = make_coef();

__device__ __forceinline__ u32 rfl(u32 v) {
    return (u32)__builtin_amdgcn_readfirstlane((int)v);   // pin wave-uniform -> SGPR
}

// ---- in-wave dtype detect: fp32 viewed as bf16 -> exponent garbage at even idx.
__device__ __forceinline__ u32 detect_bf16(const void* __restrict__ x, u32 lane) {
    float v = __bfloat162float(((const __hip_bfloat16*)x)[lane]);
    u64 bad = __ballot(!(fabsf(v) < 100.0f));
    return bad == 0ull ? 1u : 0u;
}

__device__ __forceinline__ float rd_any(const void* p, int idx, u32 isbf) {
    return isbf ? __bfloat162float(((const __hip_bfloat16*)p)[idx])
                : ((const float*)p)[idx];
}

__device__ __forceinline__ float4 rd4(const void* p, int i, u32 isbf) {
    if (isbf) {
        const u32* q = (const u32*)p;
        u32 a = q[i >> 1], b = q[(i >> 1) + 1];
        float4 r;
        r.x = __uint_as_float(a << 16); r.y = __uint_as_float(a & 0xffff0000u);
        r.z = __uint_as_float(b << 16); r.w = __uint_as_float(b & 0xffff0000u);
        return r;
    }
    return ((const float4*)p)[i >> 2];
}

// ---- prep: 32x32 LDS-tiled transpose, coalesced float4 both sides, 385 blocks.
__global__ __launch_bounds__(256) void prep_k(const void* __restrict__ x,
        const void* W1, const void* W2, const void* W3, const void* Wli,
        const void* b1, const void* b2, const void* b3, float* __restrict__ ws) {
    const u32 isbf = detect_bf16(x, threadIdx.x & 63);
    const u32 t = threadIdx.x;
    int b = blockIdx.x;

    if (b == 384) {   // tail: Wli + biases + zero rows (all coalesced)
        for (u32 e = t; e < NCLS*HID; e += 256) ws[OFF_WLI + e] = rd_any(Wli, e, isbf);
        ws[OFF_B1 + t] = rd_any(b1, t, isbf);
        ws[OFF_B2 + t] = rd_any(b2, t, isbf);
        ws[OFF_B3 + t] = rd_any(b3, t, isbf);
        ws[OFF_W1T + 1024*HID + t] = 0.f;
        ws[OFF_W2T + 256*HID + t] = 0.f;
        ws[OFF_W3T + 256*HID + t] = 0.f;
        return;
    }

    const void* src; float* dst; int srcW, h0, f0;
    if (b < 256)      { src = W1; dst = ws + OFF_W1T; srcW = FEAT; h0 = (b >> 5) * 32; f0 = (b & 31) * 32; }
    else if (b < 320) { int tb = b - 256; src = W2; dst = ws + OFF_W2T; srcW = HID; h0 = (tb >> 3) * 32; f0 = (tb & 7) * 32; }
    else              { int tb = b - 320; src = W3; dst = ws + OFF_W3T; srcW = HID; h0 = (tb >> 3) * 32; f0 = (tb & 7) * 32; }

    __shared__ float sm[32 * 36];
    {
        u32 r = t >> 3, c4 = (t & 7) * 4;
        float4 w = rd4(src, (h0 + r) * srcW + f0 + c4, isbf);
        *(float4*)&sm[r * 36 + c4] = w;
    }
    __syncthreads();
    {
        u32 f = t >> 3, h4 = (t & 7) * 4;
        float4 o;
        o.x = sm[(h4 + 0) * 36 + f];
        o.y = sm[(h4 + 1) * 36 + f];
        o.z = sm[(h4 + 2) * 36 + f];
        o.w = sm[(h4 + 3) * 36 + f];
        *(float4*)&dst[(size_t)(f0 + f) * HID + h0 + h4] = o;
    }
}

__device__ __forceinline__ u32 mbcnt64(u64 m) {
    return __builtin_amdgcn_mbcnt_hi((u32)(m >> 32),
           __builtin_amdgcn_mbcnt_lo((u32)m, 0u));
}

// ---- list builders: u16 col-index entries; branch-free prefix via weighted
// bit-plane ballots; pad to EVEN count with the zero-row col. ----

// encoder: 16 features/lane, col = 16*lane + j; zero col = 1024. returns padded np.
__device__ __forceinline__ u32 build_listE(u16* list, u32 lm, u32 lane) {
    u32 cnt = (u32)__builtin_popcount(lm);
    u32 pos = 0, n = 0;
    #pragma unroll
    for (int b = 0; b < 5; b++) {
        u64 B = __ballot(((cnt >> b) & 1u) != 0);
        pos += mbcnt64(B) << b;
        n += ((u32)__builtin_popcountll(B)) << b;
    }
    while (lm) {
        u32 j = (u32)__builtin_ctz(lm); lm &= lm - 1;
        list[pos++] = (u16)((lane << 4) + j);
    }
    u32 np = (n + 1u) & ~1u;
    if (lane == 0 && np != n) list[n] = (u16)1024;
    return np;
}

// z layers: 4 neurons/lane, col = 4*lane + j; zero col = 256; append at start
// (start must be even). returns padded end (even).
__device__ __forceinline__ u32 build_listZ(u16* list, u32 lm, u32 start, u32 lane) {
    u32 cnt = (u32)__builtin_popcount(lm);
    u64 B0 = __ballot((cnt & 1u) != 0);
    u64 B1 = __ballot((cnt & 2u) != 0);
    u64 B2 = __ballot((cnt & 4u) != 0);
    u32 pos = start + mbcnt64(B0) + 2u*mbcnt64(B1) + 4u*mbcnt64(B2);
    u32 n = start + (u32)__builtin_popcountll(B0) + 2u*(u32)__builtin_popcountll(B1)
          + 4u*(u32)__builtin_popcountll(B2);
    while (lm) {
        u32 j = (u32)__builtin_ctz(lm); lm &= lm - 1;
        list[pos++] = (u16)((lane << 2) + j);
    }
    u32 np = (n + 1u) & ~1u;
    if (lane == 0 && np != n) list[n] = (u16)256;
    return np;
}

#define GADD(AA, BB, V) do { AA += (v2f){(V).x, (V).y}; BB += (v2f){(V).z, (V).w}; } while (0)

// ---- gather (single matrix): chunks of 8 + 2-col tail. Entry words are
// wave-uniform -> readfirstlane pins them to SGPRs so unpack/shift/base-add
// run on the scalar pipe and loads take saddr form (vaddr = lane16 only). ----
__device__ __forceinline__ void gather(v2f& A, v2f& B, const float* __restrict__ Wt,
                                       const u16* __restrict__ list, u32 np, u32 lane16) {
    const char* __restrict__ base = (const char*)Wt;
    u32 c = 0;
    for (; c + 8 <= np; c += 8) {
        uint4 d = *(const uint4*)(list + c);
        u32 w0 = rfl(d.x), w1 = rfl(d.y), w2 = rfl(d.z), w3 = rfl(d.w);
        const float4 v0 = *(const float4*)(base + ((w0 & 0xffffu) << 10) + lane16);
        const float4 v1 = *(const float4*)(base + ((w0 >> 16)     << 10) + lane16);
        const float4 v2 = *(const float4*)(base + ((w1 & 0xffffu) << 10) + lane16);
        const float4 v3 = *(const float4*)(base + ((w1 >> 16)     << 10) + lane16);
        const float4 v4 = *(const float4*)(base + ((w2 & 0xffffu) << 10) + lane16);
        const float4 v5 = *(const float4*)(base + ((w2 >> 16)     << 10) + lane16);
        const float4 v6 = *(const float4*)(base + ((w3 & 0xffffu) << 10) + lane16);
        const float4 v7 = *(const float4*)(base + ((w3 >> 16)     << 10) + lane16);
        GADD(A, B, v0); GADD(A, B, v1); GADD(A, B, v2); GADD(A, B, v3);
        GADD(A, B, v4); GADD(A, B, v5); GADD(A, B, v6); GADD(A, B, v7);
    }
    for (; c < np; c += 2) {                      // 2-col units (4-B aligned)
        u32 d = rfl(*(const u32*)(list + c));
        const float4 v0 = *(const float4*)(base + ((d & 0xffffu) << 10) + lane16);
        const float4 v1 = *(const float4*)(base + ((d >> 16)     << 10) + lane16);
        GADD(A, B, v0); GADD(A, B, v1);
    }
}

// ---- dual gather over the z1 segment: same cols on W2T and W3T in one pass;
// scalar-pinned offsets shared by both matrices. ----
__device__ __forceinline__ void gather_dual(v2f& A2, v2f& B2, v2f& A3, v2f& B3,
        const float* __restrict__ W2t, const float* __restrict__ W3t,
        const u16* __restrict__ list, u32 np, u32 lane16) {
    const char* __restrict__ p2 = (const char*)W2t;
    const char* __restrict__ p3 = (const char*)W3t;
    u32 c = 0;
    for (; c + 4 <= np; c += 4) {
        uint2 d = *(const uint2*)(list + c);
        u32 w0 = rfl(d.x), w1 = rfl(d.y);
        u32 o0 = (w0 & 0xffffu) << 10, o1 = (w0 >> 16) << 10;
        u32 o2 = (w1 & 0xffffu) << 10, o3 = (w1 >> 16) << 10;
        const float4 a0 = *(const float4*)(p2 + o0 + lane16);
        const float4 a1 = *(const float4*)(p2 + o1 + lane16);
        const float4 a2 = *(const float4*)(p2 + o2 + lane16);
        const float4 a3 = *(const float4*)(p2 + o3 + lane16);
        const float4 c0 = *(const float4*)(p3 + o0 + lane16);
        const float4 c1 = *(const float4*)(p3 + o1 + lane16);
        const float4 c2 = *(const float4*)(p3 + o2 + lane16);
        const float4 c3 = *(const float4*)(p3 + o3 + lane16);
        GADD(A2, B2, a0); GADD(A2, B2, a1); GADD(A2, B2, a2); GADD(A2, B2, a3);
        GADD(A3, B3, c0); GADD(A3, B3, c1); GADD(A3, B3, c2); GADD(A3, B3, c3);
    }
    for (; c < np; c += 2) {
        u32 d = rfl(*(const u32*)(list + c));
        u32 o0 = (d & 0xffffu) << 10, o1 = (d >> 16) << 10;
        const float4 a0 = *(const float4*)(p2 + o0 + lane16);
        const float4 a1 = *(const float4*)(p2 + o1 + lane16);
        const float4 c0 = *(const float4*)(p3 + o0 + lane16);
        const float4 c1 = *(const float4*)(p3 + o1 + lane16);
        GADD(A2, B2, a0); GADD(A2, B2, a1);
        GADD(A3, B3, c0); GADD(A3, B3, c1);
    }
}

// ONE wave = ONE block = ONE batch row. Lane owns encoder features
// [16L..16L+16) and hidden neurons 4L..4L+3. Encoder spike schedule
// precomputed to LDS (2 steps/u32). z1 segment feeds L2 and L3 in one dual
// pass; z2 appended at padded np1. Empty-mask fast paths skip build+gather.
__global__ __launch_bounds__(64) void snn_k(const void* __restrict__ xin,
                                            const float* __restrict__ ws,
                                            void* __restrict__ out) {
    const u32 lane = threadIdx.x;
    const int row  = blockIdx.x;
    const u32 lane16 = lane * 16;
    const u32 isbf = detect_bf16(xin, lane);

    const float* __restrict__ W1T = ws + OFF_W1T;
    const float* __restrict__ W2T = ws + OFF_W2T;
    const float* __restrict__ W3T = ws + OFF_W3T;
    const float* __restrict__ WLI = ws + OFF_WLI;

    __shared__ u32 sched[12 * 64];               // 3 KB
    __shared__ __align__(16) u16 lE[1032];       // 2 KB
    __shared__ __align__(16) u16 lL[520];        // 1 KB

    // ---- encoder precompute: 24-step spike schedule for my 16 features ----
    {
        float xv[16];
        if (isbf) {
            const uint4* xp = (const uint4*)((const u16*)xin + (size_t)row*FEAT + lane*16);
            uint4 A = xp[0], B = xp[1];
            u32 w[8] = {A.x, A.y, A.z, A.w, B.x, B.y, B.z, B.w};
            #pragma unroll
            for (int i = 0; i < 8; i++) {
                xv[2*i]   = __uint_as_float(w[i] << 16);
                xv[2*i+1] = __uint_as_float(w[i] & 0xffff0000u);
            }
        } else {
            const float4* xp = (const float4*)((const float*)xin + (size_t)row*FEAT + lane*16);
            float4 A = xp[0], B = xp[1], C = xp[2], D = xp[3];
            float tmp[16] = {A.x,A.y,A.z,A.w,B.x,B.y,B.z,B.w,C.x,C.y,C.z,C.w,D.x,D.y,D.z,D.w};
            #pragma unroll
            for (int i = 0; i < 16; i++) xv[i] = tmp[i];
        }
        u32 smreg[12];
        #pragma unroll
        for (int i = 0; i < 12; i++) smreg[i] = 0;
        #pragma unroll
        for (int j = 0; j < 16; j++) {
            float v = 0.f;
            #pragma unroll
            for (int t = 0; t < TSTEPS; t++) {
                v = v + 0.1f * (xv[j] - v);
                bool z = v > 1.0f;
                v = z ? 0.0f : v;
                if (z) smreg[t >> 1] |= 1u << (((t & 1) << 4) + j);
            }
        }
        #pragma unroll
        for (int i = 0; i < 12; i++) sched[i * 64 + lane] = smreg[i];
        // lanes read back only their own words -> no barrier needed
    }

    float v1[4], i1[4], v2[4], i2[4], v3[4], i3[4], g[4];
    #pragma unroll
    for (int k = 0; k < 4; k++) {
        v1[k]=0.f; i1[k]=0.f; v2[k]=0.f; i2[k]=0.f; v3[k]=0.f; i3[k]=0.f; g[k]=0.f;
    }
    const u32 lane4 = lane * 4;
    const float4 b1v = *(const float4*)(ws + OFF_B1 + lane4);
    const float4 b2v = *(const float4*)(ws + OFF_B2 + lane4);
    const float4 b3v = *(const float4*)(ws + OFF_B3 + lane4);

    u32 pairreg = 0;
    for (int t = 0; t < TSTEPS; t++) {
        if ((t & 1) == 0) pairreg = sched[(t >> 1) * 64 + lane];
        const u32 lmE = (t & 1) ? (pairreg >> 16) : (pairreg & 0xffffu);

        // ---- layer 1 (skip build+gather if no encoder spikes this step) ----
        v2f accA = {b1v.x, b1v.y}, accB = {b1v.z, b1v.w};
        if (__ballot(lmE != 0u)) {
            u32 npE = build_listE(lE, lmE, lane);
            gather(accA, accB, W1T, lE, npE, lane16);
        }
        float a1[4] = {accA.x, accA.y, accB.x, accB.y};

        float o1v[4]; u32 lm1 = 0;
        #pragma unroll
        for (int kk = 0; kk < 4; kk++) {
            float vd = v1[kk] + 0.1f * (i1[kk] - v1[kk]);
            i1[kk] = i1[kk] * 0.8f;
            bool z = vd > 0.23f;
            v1[kk] = z ? 0.0f : vd;
            i1[kk] = i1[kk] + a1[kk];
            o1v[kk] = z ? 1.0f : 0.0f;
            lm1 |= (z ? 1u : 0u) << kk;
        }

        // ---- layers 2+3a: z1 cols, dual gather on W2T & W3T ----
        v2f acc2A = {b2v.x, b2v.y}, acc2B = {b2v.z, b2v.w};
        v2f acc3A = {b3v.x, b3v.y}, acc3B = {b3v.z, b3v.w};
        u32 np1 = 0;
        if (__ballot(lm1 != 0u)) {
            np1 = build_listZ(lL, lm1, 0u, lane);
            gather_dual(acc2A, acc2B, acc3A, acc3B, W2T, W3T, lL, np1, lane16);
        }
        float a2[4] = {acc2A.x, acc2A.y, acc2B.x, acc2B.y};

        float o2v[4]; u32 lm2 = 0;
        #pragma unroll
        for (int kk = 0; kk < 4; kk++) {
            float vd = v2[kk] + 0.1f * (i2[kk] - v2[kk]);
            i2[kk] = i2[kk] * 0.8f;
            bool z = vd > 0.23f;
            v2[kk] = z ? 0.0f : vd;
            i2[kk] = i2[kk] + a2[kk];
            o2v[kk] = (z ? 1.0f : 0.0f) + o1v[kk];
            lm2 |= (z ? 1u : 0u) << kk;
        }

        // ---- layer 3b: append z2 at padded np1, gather [np1, np2) on W3T.
        //      o2 = z1 + z2 via duplicate cols (exact). ----
        if (__ballot(lm2 != 0u)) {
            u32 np2 = build_listZ(lL, lm2, np1, lane);
            gather(acc3A, acc3B, W3T, lL + np1, np2 - np1, lane16);
        }
        float a3[4] = {acc3A.x, acc3A.y, acc3B.x, acc3B.y};

        const float cf = COEF.c[t];
        #pragma unroll
        for (int kk = 0; kk < 4; kk++) {
            float vd = v3[kk] + 0.1f * (i3[kk] - v3[kk]);
            i3[kk] = i3[kk] * 0.8f;
            bool z = vd > 0.23f;
            v3[kk] = z ? 0.0f : vd;
            i3[kk] = i3[kk] + a3[kk];
            float o3 = (z ? 1.0f : 0.0f) + o2v[kk];
            g[kk] += cf * o3;
        }
    }

    // ---- epilogue: vo_24[c] = sum_h g[h]*Wli[c][h] ----
    float s[NCLS];
    #pragma unroll
    for (int c = 0; c < NCLS; c++) {
        const float4 w = *(const float4*)(WLI + c*HID + lane4);
        float p = g[0]*w.x + g[1]*w.y + g[2]*w.z + g[3]*w.w;
        #pragma unroll
        for (int d = 32; d > 0; d >>= 1) p += __shfl_xor(p, d, 64);
        s[c] = p;
    }
    if (lane == 0) {
        if (isbf) {
            __hip_bfloat16* o = (__hip_bfloat16*)out + (size_t)row*NCLS;
            #pragma unroll
            for (int c = 0; c < NCLS; c++) o[c] = __float2bfloat16(s[c]);
        } else {
            float* o = (float*)out + (size_t)row*NCLS;
            #pragma unroll
            for (int c = 0; c < NCLS; c++) o[c] = s[c];
        }
    }
}

extern "C" void kernel_launch(void* const* d_in, const int* in_sizes, int n_in,
                              void* d_out, int out_size, void* d_ws, size_t ws_size,
                              hipStream_t stream) {
    const void* x   = d_in[0];
    const void* W1  = d_in[1];
    const void* b1  = d_in[2];
    const void* W2  = d_in[3];
    const void* b2  = d_in[4];
    const void* W3  = d_in[5];
    const void* b3  = d_in[6];
    const void* Wli = d_in[7];
    float* ws = (float*)d_ws;
    const int batch = in_sizes[0] / FEAT;   // 4096

    prep_k<<<385, 256, 0, stream>>>(x, W1, W2, W3, Wli, b1, b2, b3, ws);
    snn_k<<<batch, 64, 0, stream>>>(x, ws, d_out);
}